// Round 3
// baseline (11742.657 us; speedup 1.0000x reference)
//
#include <hip/hip_runtime.h>
#include <stdint.h>

#define B_    32
#define S_    1024
#define HIN   1024
#define NBLK  64
#define DBLK  16
#define HOUT  1024
#define NGATE 1152   // 64 i + 64 o + 1024 g
#define NSLICE 32    // h-column slices of 32

typedef __attribute__((ext_vector_type(8))) __bf16 bf16x8;
typedef __attribute__((ext_vector_type(4))) float  f32x4;

__device__ __forceinline__ unsigned short f2bf(float f) {
    union { float f; unsigned u; } v; v.f = f;
    return (unsigned short)((v.u + 0x7fffu + ((v.u >> 16) & 1u)) >> 16);
}
__device__ __forceinline__ float bf2f(unsigned short h) {
    union { unsigned u; float f; } v; v.u = ((unsigned)h) << 16; return v.f;
}
// fp32 -> hi+lo bf16 (v ~= hi + lo, residual <= 2^-18 |v|)
__device__ __forceinline__ void split1(float f, unsigned short& hi, unsigned short& lo) {
    hi = f2bf(f);
    lo = f2bf(f - bf2f(hi));
}

// ---------------- phase 0: split W, U, h0 into hi/lo bf16 planes ----------------
__global__ void k_init(const float* __restrict__ Wi, const float* __restrict__ Wo,
                       const float* __restrict__ Wg,
                       const float* __restrict__ Ui, const float* __restrict__ Uo,
                       const float* __restrict__ Ug, const float* __restrict__ h0,
                       unsigned short* __restrict__ WsH, unsigned short* __restrict__ WsL,
                       unsigned short* __restrict__ UsH, unsigned short* __restrict__ UsL,
                       unsigned short* __restrict__ hbH, unsigned short* __restrict__ hbL)
{
    int idx = blockIdx.x * 256 + threadIdx.x;
    const int nW = NGATE * HOUT / 4;           // 294912 quads per matrix set
    float4 v; unsigned short *dH, *dL;
    if (idx < nW) {
        int f = idx * 4; int row = f >> 10, k = f & 1023;
        const float* src = (row < 64)  ? (Wi + (size_t)row * HIN)
                         : (row < 128) ? (Wo + (size_t)(row - 64) * HIN)
                                       : (Wg + (size_t)(row - 128) * HIN);
        v = *(const float4*)(src + k);
        dH = WsH + f; dL = WsL + f;
    } else if (idx < 2 * nW) {
        int f = (idx - nW) * 4; int row = f >> 10, k = f & 1023;
        const float* src = (row < 64)  ? (Ui + (size_t)row * HOUT)
                         : (row < 128) ? (Uo + (size_t)(row - 64) * HOUT)
                                       : (Ug + (size_t)(row - 128) * HOUT);
        v = *(const float4*)(src + k);
        dH = UsH + f; dL = UsL + f;
    } else {
        int f = (idx - 2 * nW) * 4;
        if (f >= B_ * HOUT) return;
        v = *(const float4*)(h0 + f);
        dH = hbH + f; dL = hbL + f;            // slot 0
    }
    unsigned short th[4], tl[4];
    split1(v.x, th[0], tl[0]); split1(v.y, th[1], tl[1]);
    split1(v.z, th[2], tl[2]); split1(v.w, th[3], tl[3]);
    *(uint2*)dH = *(const uint2*)th;
    *(uint2*)dL = *(const uint2*)tl;
}

// ---------------- phase 1: gate pre-projection GEMM (bf16x3) ----------------
// out(m, n) = x(m,:) . Wcat(n,:) + bcat(n);  m = b*S + t, n in [0,1152)
// n <  64 -> xi stash c_out[m][n][0]; n < 128 -> xo stash c_out[m][n-64][1];
// n >= 128 -> xg  h_out[m][n-128]
#define BM 128
#define BN 128
#define BK 32
#define LDP 56

__global__ __launch_bounds__(256) void k_gates(
    const float* __restrict__ x,
    const unsigned short* __restrict__ WsH, const unsigned short* __restrict__ WsL,
    const float* __restrict__ bi, const float* __restrict__ bo, const float* __restrict__ bg,
    float* __restrict__ c_out, float* __restrict__ h_out)
{
    __shared__ unsigned short AlH[BM][LDP], AlL[BM][LDP];
    __shared__ unsigned short BlH[BN][LDP], BlL[BN][LDP];
    const int tid  = threadIdx.x;
    const int bm   = blockIdx.x, bn = blockIdx.y;
    const int wave = tid >> 6,  lane = tid & 63;
    const int l15  = lane & 15, l4 = lane >> 4;
    const int wm   = wave >> 1, wn = wave & 1;
    const int rbase = tid >> 3;          // 0..31
    const int c4    = (tid & 7) * 4;     // 0..28

    f32x4 acc[4][4] = {};

    for (int kk = 0; kk < HIN; kk += BK) {
        #pragma unroll
        for (int i = 0; i < 4; ++i) {
            int row = rbase + 32 * i;
            float4 v = *(const float4*)(x + (size_t)(bm * BM + row) * HIN + kk + c4);
            unsigned short th[4], tl[4];
            split1(v.x, th[0], tl[0]); split1(v.y, th[1], tl[1]);
            split1(v.z, th[2], tl[2]); split1(v.w, th[3], tl[3]);
            *(uint2*)&AlH[row][c4] = *(const uint2*)th;
            *(uint2*)&AlL[row][c4] = *(const uint2*)tl;
            int n = bn * BN + row;
            *(uint2*)&BlH[row][c4] = *(const uint2*)(WsH + (size_t)n * HIN + kk + c4);
            *(uint2*)&BlL[row][c4] = *(const uint2*)(WsL + (size_t)n * HIN + kk + c4);
        }
        __syncthreads();
        uint4 ah[4], al[4], bh4[4], bl4[4];
        #pragma unroll
        for (int mi = 0; mi < 4; ++mi) {
            ah[mi] = *(const uint4*)&AlH[wm * 64 + mi * 16 + l15][l4 * 8];
            al[mi] = *(const uint4*)&AlL[wm * 64 + mi * 16 + l15][l4 * 8];
        }
        #pragma unroll
        for (int ni = 0; ni < 4; ++ni) {
            bh4[ni] = *(const uint4*)&BlH[wn * 64 + ni * 16 + l15][l4 * 8];
            bl4[ni] = *(const uint4*)&BlL[wn * 64 + ni * 16 + l15][l4 * 8];
        }
        #pragma unroll
        for (int mi = 0; mi < 4; ++mi) {
            #pragma unroll
            for (int ni = 0; ni < 4; ++ni) {
                acc[mi][ni] = __builtin_amdgcn_mfma_f32_16x16x32_bf16(
                    __builtin_bit_cast(bf16x8, ah[mi]), __builtin_bit_cast(bf16x8, bh4[ni]),
                    acc[mi][ni], 0, 0, 0);
                acc[mi][ni] = __builtin_amdgcn_mfma_f32_16x16x32_bf16(
                    __builtin_bit_cast(bf16x8, ah[mi]), __builtin_bit_cast(bf16x8, bl4[ni]),
                    acc[mi][ni], 0, 0, 0);
                acc[mi][ni] = __builtin_amdgcn_mfma_f32_16x16x32_bf16(
                    __builtin_bit_cast(bf16x8, al[mi]), __builtin_bit_cast(bf16x8, bh4[ni]),
                    acc[mi][ni], 0, 0, 0);
            }
        }
        __syncthreads();
    }

    #pragma unroll
    for (int ni = 0; ni < 4; ++ni) {
        int n = bn * BN + wn * 64 + ni * 16 + l15;
        float bv = (n < 64) ? bi[n] : (n < 128) ? bo[n - 64] : bg[n - 128];
        #pragma unroll
        for (int mi = 0; mi < 4; ++mi) {
            #pragma unroll
            for (int r = 0; r < 4; ++r) {
                int m = bm * BM + wm * 64 + mi * 16 + l4 * 4 + r;
                float val = acc[mi][ni][r] + bv;
                if (n >= 128) {
                    h_out[(size_t)m * HOUT + (n - 128)] = val;
                } else if (n < 64) {
                    c_out[((size_t)m * NBLK + n) * DBLK + 0] = val;
                } else {
                    c_out[((size_t)m * NBLK + (n - 64)) * DBLK + 1] = val;
                }
            }
        }
    }
}

// ---------------- phase 2: persistent lockstep recurrence (bf16x3) ----------------
// 64 WGs: slice = bid&31 owns h-cols [32*slice,+32), group = bid>>5 owns batches
// [16*group,+16). Weight hi/lo fragments pinned in VGPRs (~256). h staged as hi/lo
// bf16 planes via agent-scope hbuf ping-pong; fp32 state; flag = monotonic counter.
__global__ __launch_bounds__(256, 1) void k_rec(
    const float* __restrict__ c0,
    float* __restrict__ c_out, float* __restrict__ h_out,
    const unsigned short* __restrict__ UsH, const unsigned short* __restrict__ UsL,
    unsigned short* __restrict__ hbH, unsigned short* __restrict__ hbL,
    unsigned int* __restrict__ cnt)
{
    __shared__ unsigned short HaH[16][1032];
    __shared__ unsigned short HaL[16][1032];
    __shared__ float pre[16][48];

    const int tid   = threadIdx.x;
    const int slice = blockIdx.x & 31;
    const int group = blockIdx.x >> 5;     // 0 or 1
    const int wave  = tid >> 6, lane = tid & 63;
    const int l15   = lane & 15, l4 = lane >> 4;

    // pin weight hi/lo B-fragments in registers (step-invariant)
    // pre cols: 0..31 = Ug rows slice*32+., 32..33 = Ui rows 2s.., 34..35 = Uo rows 2s..
    uint4 bwh[32], bwl[32];
    {
        int grow = wave * 16 + l15;
        bool valid = (wave < 3) && (grow < 36);
        int srow = (grow < 32) ? (128 + slice * 32 + grow)
                 : (grow < 34) ? (slice * 2 + (grow - 32))
                                : (64 + slice * 2 + (grow - 34));
        if (srow < 0 || srow >= NGATE) srow = 0;
        const unsigned short* ph = UsH + (size_t)srow * HOUT + l4 * 8;
        const unsigned short* pl = UsL + (size_t)srow * HOUT + l4 * 8;
        #pragma unroll
        for (int ks = 0; ks < 32; ++ks) {
            bwh[ks] = valid ? *(const uint4*)(ph + ks * 32) : make_uint4(0, 0, 0, 0);
            bwl[ks] = valid ? *(const uint4*)(pl + ks * 32) : make_uint4(0, 0, 0, 0);
        }
    }

    // per-thread cell state: 2 consecutive h-cols
    const int e0   = tid * 2;
    const int bl   = e0 >> 5;             // 0..15 batch-in-group
    const int col0 = e0 & 31;             // even, 0..30
    const int Bg   = group * 16 + bl;
    const int hcol = slice * 32 + col0;
    const int blk  = hcol >> 4, d0 = hcol & 15;
    float cr0 = c0[((size_t)Bg * NBLK + blk) * DBLK + d0];
    float cr1 = c0[((size_t)Bg * NBLK + blk) * DBLK + d0 + 1];

    unsigned int* mycnt = cnt + group;

    for (int t = 0; t < S_; ++t) {
        // early loads (independent of the flag; hide latency under spin+staging)
        const size_t rowoff = (size_t)Bg * S_ + t;
        float xg0 = h_out[rowoff * HOUT + hcol];
        float xg1 = h_out[rowoff * HOUT + hcol + 1];
        float xi  = c_out[(rowoff * NBLK + blk) * DBLK + 0];
        float xo  = c_out[(rowoff * NBLK + blk) * DBLK + 1];

        if (t > 0) {
            if (tid == 0) {
                unsigned tgt = (unsigned)(NSLICE * t);
                while (__hip_atomic_load(mycnt, __ATOMIC_ACQUIRE, __HIP_MEMORY_SCOPE_AGENT) < tgt) {}
            }
            __syncthreads();
        }

        // stage h_{t-1} hi/lo planes (16 rows x 1024 bf16 each = 4096 8B chunks)
        const unsigned long long* srcH =
            (const unsigned long long*)(hbH + ((size_t)(t & 1) * B_ + group * 16) * HOUT);
        const unsigned long long* srcL =
            (const unsigned long long*)(hbL + ((size_t)(t & 1) * B_ + group * 16) * HOUT);
        #pragma unroll
        for (int it = 0; it < 16; ++it) {
            int chunk = it * 256 + tid;
            int r = chunk >> 8, c8 = chunk & 255;
            unsigned long long vh = __hip_atomic_load(srcH + chunk,
                                        __ATOMIC_RELAXED, __HIP_MEMORY_SCOPE_AGENT);
            unsigned long long vl = __hip_atomic_load(srcL + chunk,
                                        __ATOMIC_RELAXED, __HIP_MEMORY_SCOPE_AGENT);
            *(unsigned long long*)&HaH[r][c8 * 4] = vh;
            *(unsigned long long*)&HaL[r][c8 * 4] = vl;
        }
        __syncthreads();

        if (wave < 3) {
            f32x4 acc = {0.f, 0.f, 0.f, 0.f};
            #pragma unroll
            for (int ks = 0; ks < 32; ++ks) {
                uint4 auh = *(const uint4*)&HaH[l15][ks * 32 + l4 * 8];
                uint4 aul = *(const uint4*)&HaL[l15][ks * 32 + l4 * 8];
                acc = __builtin_amdgcn_mfma_f32_16x16x32_bf16(
                        __builtin_bit_cast(bf16x8, auh), __builtin_bit_cast(bf16x8, bwh[ks]), acc, 0, 0, 0);
                acc = __builtin_amdgcn_mfma_f32_16x16x32_bf16(
                        __builtin_bit_cast(bf16x8, auh), __builtin_bit_cast(bf16x8, bwl[ks]), acc, 0, 0, 0);
                acc = __builtin_amdgcn_mfma_f32_16x16x32_bf16(
                        __builtin_bit_cast(bf16x8, aul), __builtin_bit_cast(bf16x8, bwh[ks]), acc, 0, 0, 0);
            }
            #pragma unroll
            for (int r = 0; r < 4; ++r)
                pre[l4 * 4 + r][wave * 16 + l15] = acc[r];
        }
        __syncthreads();

        // gates + state update (each thread: 2 consecutive h-cols, one block)
        float gp0 = pre[bl][col0]     + xg0;
        float gp1 = pre[bl][col0 + 1] + xg1;
        float ip  = pre[bl][32 + (col0 >> 4)] + xi;
        float op  = pre[bl][34 + (col0 >> 4)] + xo;
        float ig  = 1.f / (1.f + __expf(-ip));
        float og  = 1.f / (1.f + __expf(-op));
        cr0 += ig * tanhf(gp0);
        cr1 += ig * tanhf(gp1);
        float h0v = og * tanhf(cr0);
        float h1v = og * tanhf(cr1);

        c_out[(rowoff * NBLK + blk) * DBLK + d0]     = cr0;
        c_out[(rowoff * NBLK + blk) * DBLK + d0 + 1] = cr1;
        h_out[rowoff * HOUT + hcol]     = h0v;
        h_out[rowoff * HOUT + hcol + 1] = h1v;

        unsigned short h0h, h0l, h1h, h1l;
        split1(h0v, h0h, h0l); split1(h1v, h1h, h1l);
        size_t dsto = ((size_t)((t + 1) & 1) * B_ + Bg) * HOUT + hcol;
        __hip_atomic_store((unsigned int*)(hbH + dsto),
                           (unsigned)h0h | ((unsigned)h1h << 16),
                           __ATOMIC_RELAXED, __HIP_MEMORY_SCOPE_AGENT);
        __hip_atomic_store((unsigned int*)(hbL + dsto),
                           (unsigned)h0l | ((unsigned)h1l << 16),
                           __ATOMIC_RELAXED, __HIP_MEMORY_SCOPE_AGENT);

        __syncthreads();
        if (tid == 0)
            __hip_atomic_fetch_add(mycnt, 1u, __ATOMIC_RELEASE, __HIP_MEMORY_SCOPE_AGENT);
    }
}

// ---------------- launch ----------------
extern "C" void kernel_launch(void* const* d_in, const int* in_sizes, int n_in,
                              void* d_out, int out_size, void* d_ws, size_t ws_size,
                              hipStream_t stream) {
    const float* x  = (const float*)d_in[0];
    const float* h0 = (const float*)d_in[1];
    const float* c0 = (const float*)d_in[2];
    const float* Wi = (const float*)d_in[3];
    const float* bi = (const float*)d_in[4];
    const float* Wo = (const float*)d_in[5];
    const float* bo = (const float*)d_in[6];
    const float* Wg = (const float*)d_in[7];
    const float* bg = (const float*)d_in[8];
    const float* Ui = (const float*)d_in[9];
    const float* Uo = (const float*)d_in[10];
    const float* Ug = (const float*)d_in[11];

    float* c_out = (float*)d_out;
    float* h_out = c_out + (size_t)B_ * S_ * NBLK * DBLK;

    unsigned short* WsH  = (unsigned short*)d_ws;                    // [1152][1024]
    unsigned short* WsL  = WsH + (size_t)NGATE * HOUT;
    unsigned short* UsH  = WsL + (size_t)NGATE * HOUT;
    unsigned short* UsL  = UsH + (size_t)NGATE * HOUT;
    unsigned short* hbH  = UsL + (size_t)NGATE * HOUT;               // [2][32][1024]
    unsigned short* hbL  = hbH + (size_t)2 * B_ * HOUT;
    unsigned int*   cnt  = (unsigned int*)(hbL + (size_t)2 * B_ * HOUT);

    hipMemsetAsync(cnt, 0, 2 * sizeof(unsigned int), stream);
    k_init<<<2336, 256, 0, stream>>>(Wi, Wo, Wg, Ui, Uo, Ug, h0, WsH, WsL, UsH, UsL, hbH, hbL);
    k_gates<<<dim3((B_ * S_) / BM, NGATE / BN), 256, 0, stream>>>(
        x, WsH, WsL, bi, bo, bg, c_out, h_out);
    k_rec<<<64, 256, 0, stream>>>(c0, c_out, h_out, UsH, UsL, hbH, hbL, cnt);
}

// Round 4
// 7881.097 us; speedup vs baseline: 1.4900x; 1.4900x over previous
//
#include <hip/hip_runtime.h>
#include <stdint.h>

#define B_    32
#define S_    1024
#define HIN   1024
#define NBLK  64
#define DBLK  16
#define HOUT  1024
#define NGATE 1152   // 64 i + 64 o + 1024 g
#define NSLICE 32    // h-column slices of 32

typedef __attribute__((ext_vector_type(8))) __bf16 bf16x8;
typedef __attribute__((ext_vector_type(4))) float  f32x4;

__device__ __forceinline__ unsigned short f2bf(float f) {
    union { float f; unsigned u; } v; v.f = f;
    return (unsigned short)((v.u + 0x7fffu + ((v.u >> 16) & 1u)) >> 16);
}
__device__ __forceinline__ float bf2f(unsigned short h) {
    union { unsigned u; float f; } v; v.u = ((unsigned)h) << 16; return v.f;
}
// fp32 -> hi+lo bf16 (v ~= hi + lo, residual <= 2^-18 |v|)
__device__ __forceinline__ void split1(float f, unsigned short& hi, unsigned short& lo) {
    hi = f2bf(f);
    lo = f2bf(f - bf2f(hi));
}

// gate-row mapping for a slice: rows 0..31 = Ug[slice*32+r], 32..33 = Ui[2s..], 34..35 = Uo[2s..]
__device__ __forceinline__ int slice_row(int slice, int r) {
    return (r < 32) ? (128 + slice * 32 + r)
         : (r < 34) ? (slice * 2 + (r - 32))
                    : (64 + slice * 2 + (r - 34));
}

// ---------------- phase 0: split W, U, h0 into hi/lo bf16 planes ----------------
__global__ void k_init(const float* __restrict__ Wi, const float* __restrict__ Wo,
                       const float* __restrict__ Wg,
                       const float* __restrict__ Ui, const float* __restrict__ Uo,
                       const float* __restrict__ Ug, const float* __restrict__ h0,
                       unsigned short* __restrict__ WsH, unsigned short* __restrict__ WsL,
                       unsigned short* __restrict__ UsH, unsigned short* __restrict__ UsL,
                       unsigned short* __restrict__ hbH, unsigned short* __restrict__ hbL)
{
    int idx = blockIdx.x * 256 + threadIdx.x;
    const int nW = NGATE * HOUT / 4;           // 294912 quads per matrix set
    float4 v; unsigned short *dH, *dL;
    if (idx < nW) {
        int f = idx * 4; int row = f >> 10, k = f & 1023;
        const float* src = (row < 64)  ? (Wi + (size_t)row * HIN)
                         : (row < 128) ? (Wo + (size_t)(row - 64) * HIN)
                                       : (Wg + (size_t)(row - 128) * HIN);
        v = *(const float4*)(src + k);
        dH = WsH + f; dL = WsL + f;
    } else if (idx < 2 * nW) {
        int f = (idx - nW) * 4; int row = f >> 10, k = f & 1023;
        const float* src = (row < 64)  ? (Ui + (size_t)row * HOUT)
                         : (row < 128) ? (Uo + (size_t)(row - 64) * HOUT)
                                       : (Ug + (size_t)(row - 128) * HOUT);
        v = *(const float4*)(src + k);
        dH = UsH + f; dL = UsL + f;
    } else {
        int f = (idx - 2 * nW) * 4;
        if (f >= B_ * HOUT) return;
        v = *(const float4*)(h0 + f);
        dH = hbH + f; dL = hbL + f;            // slot 0
    }
    unsigned short th[4], tl[4];
    split1(v.x, th[0], tl[0]); split1(v.y, th[1], tl[1]);
    split1(v.z, th[2], tl[2]); split1(v.w, th[3], tl[3]);
    *(uint2*)dH = *(const uint2*)th;
    *(uint2*)dL = *(const uint2*)tl;
}

// ---------------- phase 1: gate pre-projection GEMM (bf16x3) ----------------
#define BM 128
#define BN 128
#define BK 32
#define LDP 56

__global__ __launch_bounds__(256) void k_gates(
    const float* __restrict__ x,
    const unsigned short* __restrict__ WsH, const unsigned short* __restrict__ WsL,
    const float* __restrict__ bi, const float* __restrict__ bo, const float* __restrict__ bg,
    float* __restrict__ c_out, float* __restrict__ h_out)
{
    __shared__ unsigned short AlH[BM][LDP], AlL[BM][LDP];
    __shared__ unsigned short BlH[BN][LDP], BlL[BN][LDP];
    const int tid  = threadIdx.x;
    const int bm   = blockIdx.x, bn = blockIdx.y;
    const int wave = tid >> 6,  lane = tid & 63;
    const int l15  = lane & 15, l4 = lane >> 4;
    const int wm   = wave >> 1, wn = wave & 1;
    const int rbase = tid >> 3;          // 0..31
    const int c4    = (tid & 7) * 4;     // 0..28

    f32x4 acc[4][4] = {};

    for (int kk = 0; kk < HIN; kk += BK) {
        #pragma unroll
        for (int i = 0; i < 4; ++i) {
            int row = rbase + 32 * i;
            float4 v = *(const float4*)(x + (size_t)(bm * BM + row) * HIN + kk + c4);
            unsigned short th[4], tl[4];
            split1(v.x, th[0], tl[0]); split1(v.y, th[1], tl[1]);
            split1(v.z, th[2], tl[2]); split1(v.w, th[3], tl[3]);
            *(uint2*)&AlH[row][c4] = *(const uint2*)th;
            *(uint2*)&AlL[row][c4] = *(const uint2*)tl;
            int n = bn * BN + row;
            *(uint2*)&BlH[row][c4] = *(const uint2*)(WsH + (size_t)n * HIN + kk + c4);
            *(uint2*)&BlL[row][c4] = *(const uint2*)(WsL + (size_t)n * HIN + kk + c4);
        }
        __syncthreads();
        uint4 ah[4], al[4], bh4[4], bl4[4];
        #pragma unroll
        for (int mi = 0; mi < 4; ++mi) {
            ah[mi] = *(const uint4*)&AlH[wm * 64 + mi * 16 + l15][l4 * 8];
            al[mi] = *(const uint4*)&AlL[wm * 64 + mi * 16 + l15][l4 * 8];
        }
        #pragma unroll
        for (int ni = 0; ni < 4; ++ni) {
            bh4[ni] = *(const uint4*)&BlH[wn * 64 + ni * 16 + l15][l4 * 8];
            bl4[ni] = *(const uint4*)&BlL[wn * 64 + ni * 16 + l15][l4 * 8];
        }
        #pragma unroll
        for (int mi = 0; mi < 4; ++mi) {
            #pragma unroll
            for (int ni = 0; ni < 4; ++ni) {
                acc[mi][ni] = __builtin_amdgcn_mfma_f32_16x16x32_bf16(
                    __builtin_bit_cast(bf16x8, ah[mi]), __builtin_bit_cast(bf16x8, bh4[ni]),
                    acc[mi][ni], 0, 0, 0);
                acc[mi][ni] = __builtin_amdgcn_mfma_f32_16x16x32_bf16(
                    __builtin_bit_cast(bf16x8, ah[mi]), __builtin_bit_cast(bf16x8, bl4[ni]),
                    acc[mi][ni], 0, 0, 0);
                acc[mi][ni] = __builtin_amdgcn_mfma_f32_16x16x32_bf16(
                    __builtin_bit_cast(bf16x8, al[mi]), __builtin_bit_cast(bf16x8, bh4[ni]),
                    acc[mi][ni], 0, 0, 0);
            }
        }
        __syncthreads();
    }

    #pragma unroll
    for (int ni = 0; ni < 4; ++ni) {
        int n = bn * BN + wn * 64 + ni * 16 + l15;
        float bv = (n < 64) ? bi[n] : (n < 128) ? bo[n - 64] : bg[n - 128];
        #pragma unroll
        for (int mi = 0; mi < 4; ++mi) {
            #pragma unroll
            for (int r = 0; r < 4; ++r) {
                int m = bm * BM + wm * 64 + mi * 16 + l4 * 4 + r;
                float val = acc[mi][ni][r] + bv;
                if (n >= 128) {
                    h_out[(size_t)m * HOUT + (n - 128)] = val;
                } else if (n < 64) {
                    c_out[((size_t)m * NBLK + n) * DBLK + 0] = val;
                } else {
                    c_out[((size_t)m * NBLK + (n - 64)) * DBLK + 1] = val;
                }
            }
        }
    }
}

// ---------------- phase 2: persistent lockstep recurrence (bf16x3) ----------------
// 64 WGs: slice = bid&31 owns h-cols [32*slice,+32), group = bid>>5 owns batches
// [16*group,+16). U hi-plane pinned in exactly 128 VGPRs; U lo-plane LDS-resident
// (row 36 = zeros for pad lanes). h staged hi/lo via agent-scope hbuf ping-pong.
// Sync: per-slice flags (128B apart, no RMW), relaxed poll by wave 0.
__global__ __launch_bounds__(256, 1) void k_rec(
    const float* __restrict__ c0,
    float* __restrict__ c_out, float* __restrict__ h_out,
    const unsigned short* __restrict__ UsH, const unsigned short* __restrict__ UsL,
    unsigned short* __restrict__ hbH, unsigned short* __restrict__ hbL,
    unsigned int* __restrict__ flags)
{
    __shared__ unsigned short Wlo[37][1032];   // 74.6 KB (row 36 = zeros)
    __shared__ unsigned short HaH[16][1032];   // 33 KB
    __shared__ unsigned short HaL[16][1032];   // 33 KB
    __shared__ float pre[16][48];              // 3 KB

    const int tid   = threadIdx.x;
    const int slice = blockIdx.x & 31;
    const int group = blockIdx.x >> 5;     // 0 or 1
    const int wave  = tid >> 6, lane = tid & 63;
    const int l15   = lane & 15, l4 = lane >> 4;

    // fill Wlo (lo-plane weights) into LDS; row 36 zeroed
    for (int idx = tid; idx < 37 * 128; idx += 256) {
        int row = idx >> 7, c8 = idx & 127;
        uint4 v = make_uint4(0, 0, 0, 0);
        if (row < 36)
            v = *(const uint4*)(UsL + (size_t)slice_row(slice, row) * HOUT + c8 * 8);
        *(uint4*)&Wlo[row][c8 * 8] = v;
    }

    // pin hi-plane B-fragments in exactly 128 VGPRs (waves 0-2 compute)
    const int grow  = wave * 16 + l15;
    const bool valid = (wave < 3) && (grow < 36);
    const int wrow  = valid ? grow : 36;       // LDS row for lo-plane (36 = zeros)
    uint4 bwh[32];
    {
        int srow = valid ? slice_row(slice, grow) : 0;
        const unsigned short* ph = UsH + (size_t)srow * HOUT + l4 * 8;
        #pragma unroll
        for (int ks = 0; ks < 32; ++ks)
            bwh[ks] = valid ? *(const uint4*)(ph + ks * 32) : make_uint4(0, 0, 0, 0);
    }

    // per-thread cell state: 2 consecutive h-cols
    const int e0   = tid * 2;
    const int bl   = e0 >> 5;             // 0..15 batch-in-group
    const int col0 = e0 & 31;             // even, 0..30
    const int Bg   = group * 16 + bl;
    const int hcol = slice * 32 + col0;
    const int blk  = hcol >> 4, d0 = hcol & 15;
    float cr0 = c0[((size_t)Bg * NBLK + blk) * DBLK + d0];
    float cr1 = c0[((size_t)Bg * NBLK + blk) * DBLK + d0 + 1];

    unsigned int* myflag = flags + ((size_t)(group * NSLICE + slice)) * 32;  // 128B apart
    unsigned int* pollfl = flags + ((size_t)(group * NSLICE + (lane & 31))) * 32;

    __syncthreads();   // Wlo ready

    for (int t = 0; t < S_; ++t) {
        // early loads (own-WG data; hidden under poll+staging)
        const size_t rowoff = (size_t)Bg * S_ + t;
        float xg0 = h_out[rowoff * HOUT + hcol];
        float xg1 = h_out[rowoff * HOUT + hcol + 1];
        float xi  = c_out[(rowoff * NBLK + blk) * DBLK + 0];
        float xo  = c_out[(rowoff * NBLK + blk) * DBLK + 1];

        if (t > 0) {
            if (wave == 0) {
                unsigned v;
                do {
                    v = __hip_atomic_load(pollfl, __ATOMIC_RELAXED, __HIP_MEMORY_SCOPE_AGENT);
                } while (!__all((int)(v >= (unsigned)t)));
            }
            __syncthreads();
        }

        // stage h_{t-1} hi/lo planes (16 rows x 1024 bf16 = 2048 8B chunks per plane)
        const unsigned long long* srcH =
            (const unsigned long long*)(hbH + ((size_t)(t & 1) * B_ + group * 16) * HOUT);
        const unsigned long long* srcL =
            (const unsigned long long*)(hbL + ((size_t)(t & 1) * B_ + group * 16) * HOUT);
        #pragma unroll
        for (int it = 0; it < 16; ++it) {
            int chunk = it * 256 + tid;           // 0..4095
            int r = chunk >> 8, c8 = chunk & 255;
            unsigned long long vh = __hip_atomic_load(srcH + chunk,
                                        __ATOMIC_RELAXED, __HIP_MEMORY_SCOPE_AGENT);
            unsigned long long vl = __hip_atomic_load(srcL + chunk,
                                        __ATOMIC_RELAXED, __HIP_MEMORY_SCOPE_AGENT);
            *(unsigned long long*)&HaH[r][c8 * 4] = vh;
            *(unsigned long long*)&HaL[r][c8 * 4] = vl;
        }
        __syncthreads();

        if (wave < 3) {
            f32x4 acc = {0.f, 0.f, 0.f, 0.f};
            #pragma unroll
            for (int ks = 0; ks < 32; ++ks) {
                uint4 auh = *(const uint4*)&HaH[l15][ks * 32 + l4 * 8];
                uint4 aul = *(const uint4*)&HaL[l15][ks * 32 + l4 * 8];
                uint4 bl_ = *(const uint4*)&Wlo[wrow][ks * 32 + l4 * 8];
                acc = __builtin_amdgcn_mfma_f32_16x16x32_bf16(
                        __builtin_bit_cast(bf16x8, auh), __builtin_bit_cast(bf16x8, bwh[ks]), acc, 0, 0, 0);
                acc = __builtin_amdgcn_mfma_f32_16x16x32_bf16(
                        __builtin_bit_cast(bf16x8, aul), __builtin_bit_cast(bf16x8, bwh[ks]), acc, 0, 0, 0);
                acc = __builtin_amdgcn_mfma_f32_16x16x32_bf16(
                        __builtin_bit_cast(bf16x8, auh), __builtin_bit_cast(bf16x8, bl_), acc, 0, 0, 0);
            }
            #pragma unroll
            for (int r = 0; r < 4; ++r)
                pre[l4 * 4 + r][wave * 16 + l15] = acc[r];
        }
        __syncthreads();

        // gates + state update (each thread: 2 consecutive h-cols, one block)
        float gp0 = pre[bl][col0]     + xg0;
        float gp1 = pre[bl][col0 + 1] + xg1;
        float ip  = pre[bl][32 + (col0 >> 4)] + xi;
        float op  = pre[bl][34 + (col0 >> 4)] + xo;
        float ig  = 1.f / (1.f + __expf(-ip));
        float og  = 1.f / (1.f + __expf(-op));
        cr0 += ig * tanhf(gp0);
        cr1 += ig * tanhf(gp1);
        float h0v = og * tanhf(cr0);
        float h1v = og * tanhf(cr1);

        // publish h (agent-scope, LLC) FIRST — this is the inter-WG critical path
        unsigned short h0h, h0l, h1h, h1l;
        split1(h0v, h0h, h0l); split1(h1v, h1h, h1l);
        size_t dsto = ((size_t)((t + 1) & 1) * B_ + Bg) * HOUT + hcol;
        __hip_atomic_store((unsigned int*)(hbH + dsto),
                           (unsigned)h0h | ((unsigned)h1h << 16),
                           __ATOMIC_RELAXED, __HIP_MEMORY_SCOPE_AGENT);
        __hip_atomic_store((unsigned int*)(hbL + dsto),
                           (unsigned)h0l | ((unsigned)h1l << 16),
                           __ATOMIC_RELAXED, __HIP_MEMORY_SCOPE_AGENT);

        asm volatile("s_waitcnt vmcnt(0)" ::: "memory");
        __syncthreads();
        if (tid == 0)
            __hip_atomic_store(myflag, (unsigned)(t + 1),
                               __ATOMIC_RELAXED, __HIP_MEMORY_SCOPE_AGENT);

        // outputs AFTER the flag publish (off the critical path)
        c_out[(rowoff * NBLK + blk) * DBLK + d0]     = cr0;
        c_out[(rowoff * NBLK + blk) * DBLK + d0 + 1] = cr1;
        h_out[rowoff * HOUT + hcol]     = h0v;
        h_out[rowoff * HOUT + hcol + 1] = h1v;
    }
}

// ---------------- launch ----------------
extern "C" void kernel_launch(void* const* d_in, const int* in_sizes, int n_in,
                              void* d_out, int out_size, void* d_ws, size_t ws_size,
                              hipStream_t stream) {
    const float* x  = (const float*)d_in[0];
    const float* h0 = (const float*)d_in[1];
    const float* c0 = (const float*)d_in[2];
    const float* Wi = (const float*)d_in[3];
    const float* bi = (const float*)d_in[4];
    const float* Wo = (const float*)d_in[5];
    const float* bo = (const float*)d_in[6];
    const float* Wg = (const float*)d_in[7];
    const float* bg = (const float*)d_in[8];
    const float* Ui = (const float*)d_in[9];
    const float* Uo = (const float*)d_in[10];
    const float* Ug = (const float*)d_in[11];

    float* c_out = (float*)d_out;
    float* h_out = c_out + (size_t)B_ * S_ * NBLK * DBLK;

    unsigned short* WsH  = (unsigned short*)d_ws;                    // [1152][1024]
    unsigned short* WsL  = WsH + (size_t)NGATE * HOUT;
    unsigned short* UsH  = WsL + (size_t)NGATE * HOUT;
    unsigned short* UsL  = UsH + (size_t)NGATE * HOUT;
    unsigned short* hbH  = UsL + (size_t)NGATE * HOUT;               // [2][32][1024]
    unsigned short* hbL  = hbH + (size_t)2 * B_ * HOUT;
    unsigned int*   flags = (unsigned int*)(hbL + (size_t)2 * B_ * HOUT); // 64 x 128B

    hipMemsetAsync(flags, 0, 64 * 32 * sizeof(unsigned int), stream);
    k_init<<<2336, 256, 0, stream>>>(Wi, Wo, Wg, Ui, Uo, Ug, h0, WsH, WsL, UsH, UsL, hbH, hbL);
    k_gates<<<dim3((B_ * S_) / BM, NGATE / BN), 256, 0, stream>>>(
        x, WsH, WsL, bi, bo, bg, c_out, h_out);
    k_rec<<<64, 256, 0, stream>>>(c0, c_out, h_out, UsH, UsL, hbH, hbL, flags);
}